// Round 3
// baseline (265.686 us; speedup 1.0000x reference)
//
#include <hip/hip_runtime.h>
#include <stdint.h>

typedef unsigned short u16;
typedef __attribute__((ext_vector_type(8))) short short8;   // 8 bf16 = 4 VGPRs (MFMA A/B frag)
typedef __attribute__((ext_vector_type(4))) short short4v;
typedef __attribute__((ext_vector_type(4))) float float4v;  // MFMA C/D frag

#define NB 2
#define NT 2048
#define NC 1024
#define NH 16
#define ND 64
#define NM (NB*NT)   // 4096 rows total

// fine-grained barriers: never drain the prefetch queue (vmcnt(4) leaves the
// 4 just-issued next-chunk global_load_lds in flight across the barrier)
#define BAR_PREF  asm volatile("s_waitcnt vmcnt(4) lgkmcnt(0)\n\ts_barrier" ::: "memory")
#define BAR_LAST  asm volatile("s_waitcnt vmcnt(0) lgkmcnt(0)\n\ts_barrier" ::: "memory")
#define BAR_PLAIN asm volatile("s_barrier" ::: "memory")

// fp32 -> bf16 round-to-nearest-even
__device__ __forceinline__ u16 f2bf(float f) {
  union { float f; uint32_t u; } v; v.f = f;
  uint32_t u = v.u;
  u += 0x7fffu + ((u >> 16) & 1u);
  return (u16)(u >> 16);
}
__device__ __forceinline__ float bf2f(u16 u) {
  union { uint32_t u; float f; } v; v.u = ((uint32_t)u) << 16; return v.f;
}

// async global->LDS, 16B per lane; lds dest must be wave-uniform (lane i -> lds + i*16B)
__device__ __forceinline__ void gld_lds16(const u16* g, u16* lds) {
  __builtin_amdgcn_global_load_lds(
      (const __attribute__((address_space(1))) uint32_t*)g,
      (__attribute__((address_space(3))) uint32_t*)lds,
      16, 0, 0);
}

// ---------------- cast: x, Wk, Wq, Wv, Wp -> bf16 ----------------
__global__ __launch_bounds__(256) void cast_all(
    const float* __restrict__ x,  const float* __restrict__ wk,
    const float* __restrict__ wq, const float* __restrict__ wv,
    const float* __restrict__ wp,
    u16* __restrict__ xb, u16* __restrict__ wkb, u16* __restrict__ wqb,
    u16* __restrict__ wvb, u16* __restrict__ wpb) {
  const int NX = NM * NC / 4;   // 1048576 float4s
  const int NW = NC * NC / 4;   // 262144 float4s
  int i = blockIdx.x * 256 + threadIdx.x;
  const float* src; u16* dst; int off;
  if (i < NX)            { src = x;  dst = xb;  off = i; }
  else if (i < NX+NW)    { src = wk; dst = wkb; off = i - NX; }
  else if (i < NX+2*NW)  { src = wq; dst = wqb; off = i - NX - NW; }
  else if (i < NX+3*NW)  { src = wv; dst = wvb; off = i - NX - 2*NW; }
  else if (i < NX+4*NW)  { src = wp; dst = wpb; off = i - NX - 3*NW; }
  else return;
  float4v f = ((const float4v*)src)[off];
  short4v o;
  o.x = (short)f2bf(f.x); o.y = (short)f2bf(f.y);
  o.z = (short)f2bf(f.z); o.w = (short)f2bf(f.w);
  ((short4v*)dst)[off] = o;
}

// ---------------- shared 128x128xK GEMM core: C = A * W^T ----------------
__device__ __forceinline__ void gemm_tile(
    const u16* __restrict__ A_tile, const u16* __restrict__ W_tile,
    u16* As, u16* Bs, float4v (&acc)[4][4]) {
  const int tid  = threadIdx.x;
  const int wave = tid >> 6, lane = tid & 63;
  const int quad = lane >> 4, l15 = lane & 15;
  const int wm = wave >> 1, wn = wave & 1;
  const int c8 = lane & 7, r8 = lane >> 3;

#pragma unroll
  for (int i = 0; i < 4; i++)
#pragma unroll
    for (int j = 0; j < 4; j++) acc[i][j] = (float4v){0.f, 0.f, 0.f, 0.f};

  for (int k0 = 0; k0 < NC; k0 += 64) {
#pragma unroll
    for (int i = 0; i < 4; i++) {
      int row = wave * 32 + i * 8 + r8;
      int gc  = c8 ^ (row & 7);
      gld_lds16(A_tile + row * NC + k0 + gc * 8, As + (wave * 32 + i * 8) * 64);
      gld_lds16(W_tile + row * NC + k0 + gc * 8, Bs + (wave * 32 + i * 8) * 64);
    }
    __syncthreads();
#pragma unroll
    for (int kk = 0; kk < 2; kk++) {
      short8 af[4], bf[4];
#pragma unroll
      for (int mt = 0; mt < 4; mt++) {
        int row = wm * 64 + mt * 16 + l15;
        int ch  = (kk * 4 + quad) ^ (row & 7);
        af[mt] = *(const short8*)(As + row * 64 + ch * 8);
      }
#pragma unroll
      for (int nt = 0; nt < 4; nt++) {
        int row = wn * 64 + nt * 16 + l15;
        int ch  = (kk * 4 + quad) ^ (row & 7);
        bf[nt] = *(const short8*)(Bs + row * 64 + ch * 8);
      }
#pragma unroll
      for (int mt = 0; mt < 4; mt++)
#pragma unroll
        for (int nt = 0; nt < 4; nt++)
          acc[mt][nt] = __builtin_amdgcn_mfma_f32_16x16x32_bf16(af[mt], bf[nt], acc[mt][nt], 0, 0, 0);
    }
    __syncthreads();
  }
}

// ---------------- fused QKV projection ----------------
__global__ __launch_bounds__(256) void qkv_gemm(
    const u16* __restrict__ xb,
    const u16* __restrict__ wqb, const u16* __restrict__ wkb, const u16* __restrict__ wvb,
    const float* __restrict__ bq, const float* __restrict__ bk, const float* __restrict__ bv,
    u16* __restrict__ Q, u16* __restrict__ K, u16* __restrict__ Vb) {
  __shared__ u16 As[128 * 64];
  __shared__ u16 Bs[128 * 64];
  const int nb  = blockIdx.x;
  const int mat = nb >> 3;            // 0=Q 1=K 2=V
  const int n0  = (nb & 7) * 128;
  const int m0  = blockIdx.y * 128;
  const u16*   W    = (mat == 0) ? wqb : (mat == 1) ? wkb : wvb;
  const float* bias = (mat == 0) ? bq  : (mat == 1) ? bk  : bv;
  u16* dst = (mat == 0) ? Q : (mat == 1) ? K : Vb;

  float4v acc[4][4];
  gemm_tile(xb + m0 * NC, W + n0 * NC, As, Bs, acc);

  const int tid = threadIdx.x, wave = tid >> 6, lane = tid & 63;
  const int quad = lane >> 4, l15 = lane & 15;
  const int wm = wave >> 1, wn = wave & 1;
#pragma unroll
  for (int nt = 0; nt < 4; nt++) {
    int col = n0 + wn * 64 + nt * 16 + l15;
    float bval = bias[col];
#pragma unroll
    for (int mt = 0; mt < 4; mt++) {
      int rowb = m0 + wm * 64 + mt * 16 + quad * 4;
#pragma unroll
      for (int r = 0; r < 4; r++)
        dst[(size_t)(rowb + r) * NC + col] = f2bf(acc[mt][nt][r] + bval);
    }
  }
}

// ---------------- V transpose: [4096,1024] -> [B,H,D,T] ----------------
__global__ __launch_bounds__(256) void vtrans(const u16* __restrict__ V, u16* __restrict__ Vt) {
  __shared__ u16 tl[64 * 64];
  const int tid = threadIdx.x;
  const int bh = blockIdx.y, b = bh >> 4, h = bh & 15;
  const int t0 = blockIdx.x * 64;
#pragma unroll
  for (int it = 0; it < 2; it++) {
    int idx = it * 256 + tid;        // 0..511
    int row = idx >> 3;              // t within tile
    int ch  = idx & 7;               // d chunk
    short8 vv = *(const short8*)(V + (size_t)(b * NT + t0 + row) * NC + h * ND + ch * 8);
    int xr = (row >> 3) ^ ch;
    int off = xr * 8 + (row & 7);
#pragma unroll
    for (int j = 0; j < 8; j++) tl[(ch * 8 + j) * 64 + off] = (u16)vv[j];
  }
  __syncthreads();
#pragma unroll
  for (int it = 0; it < 2; it++) {
    int idx = it * 256 + tid;
    int d  = idx >> 3;
    int tc = idx & 7;
    short8 o = *(const short8*)(tl + d * 64 + ((tc ^ ((d >> 3) & 7)) << 3));
    *(short8*)(Vt + (size_t)(bh * ND + d) * NT + t0 + tc * 8) = o;
  }
}

// ---------------- flash attention (causal), 128-row tiles, 2 m-subtiles/wave ----------
// grid (24, B*H): x<8:        tile=x, chunks 0..2x+1, direct write.
//                 x in [8,16): tile=x, seg0 = chunks 0..15 (partial).
//                 x in [16,24): tile=x-8, seg1 = chunks 16..2t+1 (partial, diagonal).
__global__ __launch_bounds__(256) void attn(
    const u16* __restrict__ Q, const u16* __restrict__ K,
    const u16* __restrict__ Vt, u16* __restrict__ O,
    u16* __restrict__ Opart, float* __restrict__ Mpart, float* __restrict__ Lpart) {
  __shared__ u16 Kc[2][64 * 64];
  __shared__ u16 Vc[2][64 * 64];
  __shared__ u16 Pl[4][2][16 * 64];

  const int tid = threadIdx.x, wave = tid >> 6, lane = tid & 63;
  const int quad = lane >> 4, l15 = lane & 15;
  const int c8 = lane & 7, r8 = lane >> 3;
  const int bh = blockIdx.y, b = bh >> 4, h = bh & 15;
  const int x = blockIdx.x;
  int tile, c_lo, c_hi, seg; bool partial;
  if (x < 8)       { tile = x;     c_lo = 0;  c_hi = 2 * x + 1;    partial = false; seg = 0; }
  else if (x < 16) { tile = x;     c_lo = 0;  c_hi = 15;           partial = true;  seg = 0; }
  else             { tile = x - 8; c_lo = 16; c_hi = 2 * tile + 1; partial = true;  seg = 1; }
  const int qb0 = tile * 128 + wave * 32;   // wave's first q row (2 subtiles of 16)
  const float scale = 0.125f;  // 1/sqrt(64)

  short8 qf[2][2];
#pragma unroll
  for (int j = 0; j < 2; j++) {
    const u16* qrow = Q + (size_t)(b * NT + qb0 + j * 16 + l15) * NC + h * ND + quad * 8;
    qf[j][0] = *(const short8*)(qrow);
    qf[j][1] = *(const short8*)(qrow + 32);
  }

  float m_r[2][4], l_r[2][4];
  float4v o_acc[2][4];
#pragma unroll
  for (int j = 0; j < 2; j++)
#pragma unroll
    for (int r = 0; r < 4; r++) { m_r[j][r] = -1e30f; l_r[j][r] = 0.f; }
#pragma unroll
  for (int j = 0; j < 2; j++)
#pragma unroll
    for (int dt = 0; dt < 4; dt++) o_acc[j][dt] = (float4v){0.f, 0.f, 0.f, 0.f};

  auto stage = [&](int ci, int p) {
#pragma unroll
    for (int ii = 0; ii < 2; ii++) {
      int row = wave * 16 + ii * 8 + r8;
      int gc  = c8 ^ (row & 7);
      gld_lds16(K  + (size_t)(b * NT + ci * 64 + row) * NC + h * ND + gc * 8,
                Kc[p] + (wave * 16 + ii * 8) * 64);
      gld_lds16(Vt + (size_t)(bh * ND + row) * NT + ci * 64 + gc * 8,
                Vc[p] + (wave * 16 + ii * 8) * 64);
    }
  };

  stage(c_lo, 0);
  for (int i = c_lo; i <= c_hi; i++) {
    const int p = (i - c_lo) & 1;
    if (i < c_hi) { stage(i + 1, p ^ 1); BAR_PREF; }
    else          { BAR_LAST; }
    const u16* Ks = Kc[p];
    const u16* Vs = Vc[p];

    // S = Q K^T for both subtiles; K fragments shared
    float sv[2][4][4];
#pragma unroll
    for (int sub = 0; sub < 4; sub++) {
      float4v a0 = (float4v){0.f, 0.f, 0.f, 0.f};
      float4v a1 = (float4v){0.f, 0.f, 0.f, 0.f};
#pragma unroll
      for (int kk = 0; kk < 2; kk++) {
        int row = sub * 16 + l15;
        int ch  = (kk * 4 + quad) ^ (row & 7);
        short8 kf = *(const short8*)(Ks + row * 64 + ch * 8);
        a0 = __builtin_amdgcn_mfma_f32_16x16x32_bf16(qf[0][kk], kf, a0, 0, 0, 0);
        a1 = __builtin_amdgcn_mfma_f32_16x16x32_bf16(qf[1][kk], kf, a1, 0, 0, 0);
      }
#pragma unroll
      for (int j = 0; j < 2; j++) {
        const int qbaseJ = qb0 + j * 16;
        const bool mj = (i * 64 + 63 > qbaseJ);   // wave-uniform
        float4v& a = (j == 0) ? a0 : a1;
#pragma unroll
        for (int r = 0; r < 4; r++) {
          float v = a[r] * scale;
          if (mj) {
            int sg = i * 64 + sub * 16 + l15;
            int qg = qbaseJ + quad * 4 + r;
            if (sg > qg) v = -1e30f;
          }
          sv[j][sub][r] = v;
        }
      }
    }

    // online softmax (two independent chains -> interleaved latency hiding)
    float mx[2][4];
#pragma unroll
    for (int j = 0; j < 2; j++)
#pragma unroll
      for (int r = 0; r < 4; r++)
        mx[j][r] = fmaxf(fmaxf(sv[j][0][r], sv[j][1][r]), fmaxf(sv[j][2][r], sv[j][3][r]));
#pragma unroll
    for (int msk = 1; msk < 16; msk <<= 1)
#pragma unroll
      for (int j = 0; j < 2; j++)
#pragma unroll
        for (int r = 0; r < 4; r++)
          mx[j][r] = fmaxf(mx[j][r], __shfl_xor(mx[j][r], msk));

    float mnew[2][4], alpha[2][4], rs[2][4];
#pragma unroll
    for (int j = 0; j < 2; j++)
#pragma unroll
      for (int r = 0; r < 4; r++) {
        mnew[j][r]  = fmaxf(m_r[j][r], mx[j][r]);
        alpha[j][r] = __expf(m_r[j][r] - mnew[j][r]);
        rs[j][r]    = 0.f;
      }

#pragma unroll
    for (int sub = 0; sub < 4; sub++)
#pragma unroll
      for (int j = 0; j < 2; j++)
#pragma unroll
        for (int r = 0; r < 4; r++) {
          float pv = __expf(sv[j][sub][r] - mnew[j][r]);
          rs[j][r] += pv;
          int row  = quad * 4 + r;
          int colb = sub * 16 + l15;
          int ch   = (colb >> 3) ^ (row & 7);
          Pl[wave][j][row * 64 + ch * 8 + (colb & 7)] = f2bf(pv);
        }
#pragma unroll
    for (int msk = 1; msk < 16; msk <<= 1)
#pragma unroll
      for (int j = 0; j < 2; j++)
#pragma unroll
        for (int r = 0; r < 4; r++)
          rs[j][r] += __shfl_xor(rs[j][r], msk);
#pragma unroll
    for (int j = 0; j < 2; j++)
#pragma unroll
      for (int r = 0; r < 4; r++) {
        l_r[j][r] = l_r[j][r] * alpha[j][r] + rs[j][r];
        m_r[j][r] = mnew[j][r];
      }

    asm volatile("s_waitcnt lgkmcnt(0)" ::: "memory");  // own-wave P writes visible

#pragma unroll
    for (int j = 0; j < 2; j++)
#pragma unroll
      for (int dt = 0; dt < 4; dt++)
#pragma unroll
        for (int r = 0; r < 4; r++)
          o_acc[j][dt][r] *= alpha[j][r];

    // O += P * V; V fragments shared between subtiles
#pragma unroll
    for (int half = 0; half < 2; half++) {
      int chp = (half * 4 + quad) ^ (l15 & 7);
      short8 pf0 = *(const short8*)(Pl[wave][0] + l15 * 64 + chp * 8);
      short8 pf1 = *(const short8*)(Pl[wave][1] + l15 * 64 + chp * 8);
#pragma unroll
      for (int dt = 0; dt < 4; dt++) {
        int row = dt * 16 + l15;
        int ch  = (half * 4 + quad) ^ (row & 7);
        short8 vf = *(const short8*)(Vs + row * 64 + ch * 8);
        o_acc[0][dt] = __builtin_amdgcn_mfma_f32_16x16x32_bf16(pf0, vf, o_acc[0][dt], 0, 0, 0);
        o_acc[1][dt] = __builtin_amdgcn_mfma_f32_16x16x32_bf16(pf1, vf, o_acc[1][dt], 0, 0, 0);
      }
    }
    BAR_PLAIN;  // all waves done reading buf p before next iter's DMA overwrites it
  }

  if (!partial) {
#pragma unroll
    for (int j = 0; j < 2; j++)
#pragma unroll
      for (int dt = 0; dt < 4; dt++)
#pragma unroll
        for (int r = 0; r < 4; r++) {
          int qg = qb0 + j * 16 + quad * 4 + r;
          int d  = dt * 16 + l15;
          O[(size_t)(b * NT + qg) * NC + h * ND + d] = f2bf(o_acc[j][dt][r] / l_r[j][r]);
        }
  } else {
    int slab = bh * 8 + (tile - 8);
    u16* ob = Opart + ((size_t)seg * 256 + slab) * 8192;
#pragma unroll
    for (int j = 0; j < 2; j++)
#pragma unroll
      for (int dt = 0; dt < 4; dt++)
#pragma unroll
        for (int r = 0; r < 4; r++) {
          int row = wave * 32 + j * 16 + quad * 4 + r;
          int d   = dt * 16 + l15;
          ob[row * 64 + d] = f2bf(o_acc[j][dt][r]);   // unnormalized partial
        }
    if (l15 == 0) {
#pragma unroll
      for (int j = 0; j < 2; j++)
#pragma unroll
        for (int r = 0; r < 4; r++) {
          int row = wave * 32 + j * 16 + quad * 4 + r;
          Mpart[(seg * 256 + slab) * 128 + row] = m_r[j][r];
          Lpart[(seg * 256 + slab) * 128 + row] = l_r[j][r];
        }
    }
  }
}

// ---------------- combine split-s partials ----------------
__global__ __launch_bounds__(256) void combine(
    const u16* __restrict__ Opart, const float* __restrict__ Mp,
    const float* __restrict__ Lp, u16* __restrict__ O) {
  int idx  = blockIdx.x * 256 + threadIdx.x;   // 0..2M-1
  int slab = idx >> 13;
  int rem  = idx & 8191;
  int row  = rem >> 6, d = rem & 63;
  float m0 = Mp[slab * 128 + row], m1 = Mp[(256 + slab) * 128 + row];
  float l0 = Lp[slab * 128 + row], l1 = Lp[(256 + slab) * 128 + row];
  float m  = fmaxf(m0, m1);
  float w0 = __expf(m0 - m), w1 = __expf(m1 - m);
  float o0 = bf2f(Opart[(size_t)slab * 8192 + rem]);
  float o1 = bf2f(Opart[(size_t)(256 + slab) * 8192 + rem]);
  float o  = (w0 * o0 + w1 * o1) / (w0 * l0 + w1 * l1);
  int bh = slab >> 3, tile = 8 + (slab & 7);
  int b = bh >> 4, h = bh & 15;
  int t = tile * 128 + row;
  O[(size_t)(b * NT + t) * NC + h * ND + d] = f2bf(o);
}

// ---------------- output projection ----------------
__global__ __launch_bounds__(256) void out_gemm(
    const u16* __restrict__ Ob, const u16* __restrict__ wpb,
    const float* __restrict__ bp, float* __restrict__ out) {
  __shared__ u16 As[128 * 64];
  __shared__ u16 Bs[128 * 64];
  const int n0 = blockIdx.x * 128;
  const int m0 = blockIdx.y * 128;
  float4v acc[4][4];
  gemm_tile(Ob + m0 * NC, wpb + n0 * NC, As, Bs, acc);

  const int tid = threadIdx.x, wave = tid >> 6, lane = tid & 63;
  const int quad = lane >> 4, l15 = lane & 15;
  const int wm = wave >> 1, wn = wave & 1;
#pragma unroll
  for (int nt = 0; nt < 4; nt++) {
    int col = n0 + wn * 64 + nt * 16 + l15;
    float bval = bp[col];
#pragma unroll
    for (int mt = 0; mt < 4; mt++) {
      int rowb = m0 + wm * 64 + mt * 16 + quad * 4;
#pragma unroll
      for (int r = 0; r < 4; r++)
        out[(rowb + r) * NC + col] = acc[mt][nt][r] + bval;
    }
  }
}

extern "C" void kernel_launch(void* const* d_in, const int* in_sizes, int n_in,
                              void* d_out, int out_size, void* d_ws, size_t ws_size,
                              hipStream_t stream) {
  // setup_inputs order: x, Wk, bk, Wq, bq, Wv, bv, Wp, bp
  const float* x  = (const float*)d_in[0];
  const float* Wk = (const float*)d_in[1];
  const float* bk = (const float*)d_in[2];
  const float* Wq = (const float*)d_in[3];
  const float* bq = (const float*)d_in[4];
  const float* Wv = (const float*)d_in[5];
  const float* bv = (const float*)d_in[6];
  const float* Wp = (const float*)d_in[7];
  const float* bp = (const float*)d_in[8];
  float* out = (float*)d_out;

  uint8_t* ws = (uint8_t*)d_ws;
  const size_t MB = 1u << 20;
  u16* xb    = (u16*)(ws + 0 * MB);
  u16* wkb   = (u16*)(ws + 8 * MB);
  u16* wqb   = (u16*)(ws + 10 * MB);
  u16* wvb   = (u16*)(ws + 12 * MB);
  u16* wpb   = (u16*)(ws + 14 * MB);
  u16* Qb    = (u16*)(ws + 16 * MB);
  u16* Kb    = (u16*)(ws + 24 * MB);
  u16* Vtb   = (u16*)(ws + 32 * MB);   // [B,H,D,T]
  u16* Vb    = (u16*)(ws + 40 * MB);   // row-major V (transient)
  u16* Ob    = (u16*)(ws + 40 * MB);   // attention output, overwrites Vb
  u16* Opart = (u16*)(ws + 0 * MB);    // reuses xb region (8 MB)
  float* Mpart = (float*)(ws + 8 * MB);               // 256 KB
  float* Lpart = (float*)(ws + 8 * MB + 256 * 1024);  // 256 KB

  cast_all<<<8192, 256, 0, stream>>>(x, Wk, Wq, Wv, Wp, xb, wkb, wqb, wvb, wpb);
  qkv_gemm<<<dim3(24, 32), 256, 0, stream>>>(xb, wqb, wkb, wvb, bq, bk, bv, Qb, Kb, Vb);
  vtrans<<<dim3(32, 32), 256, 0, stream>>>(Vb, Vtb);
  attn<<<dim3(24, 32), 256, 0, stream>>>(Qb, Kb, Vtb, Ob, Opart, Mpart, Lpart);
  combine<<<8192, 256, 0, stream>>>(Opart, Mpart, Lpart, Ob);
  out_gemm<<<dim3(8, 32), 256, 0, stream>>>(Ob, wpb, bp, out);
}

// Round 4
// 229.724 us; speedup vs baseline: 1.1565x; 1.1565x over previous
//
#include <hip/hip_runtime.h>
#include <stdint.h>

typedef unsigned short u16;
typedef __attribute__((ext_vector_type(8))) short short8;   // 8 bf16 (4 VGPRs) MFMA A/B frag K=32
typedef __attribute__((ext_vector_type(4))) short short4v;  // 4 bf16 (2 VGPRs) MFMA A/B frag K=16
typedef __attribute__((ext_vector_type(4))) float float4v;  // MFMA C/D frag

#define NB 2
#define NT 2048
#define NC 1024
#define NH 16
#define ND 64
#define NM (NB*NT)   // 4096 rows total

// 16x16x16 bf16 MFMA (2-VGPR operands). Builtin if present, else raw asm.
#if defined(__has_builtin)
#if __has_builtin(__builtin_amdgcn_mfma_f32_16x16x16bf16_1k)
#define MFMA16(a, b, c) __builtin_amdgcn_mfma_f32_16x16x16bf16_1k(a, b, c, 0, 0, 0)
#endif
#endif
#ifndef MFMA16
static __device__ __forceinline__ float4v mfma16_asm(short4v a, short4v b, float4v c) {
  asm volatile("v_mfma_f32_16x16x16_bf16 %0, %1, %2, %0" : "+v"(c) : "v"(a), "v"(b));
  return c;
}
#define MFMA16(a, b, c) mfma16_asm(a, b, c)
#endif

// fine-grained barriers: never drain the prefetch queue (vmcnt(4) leaves the
// 4 just-issued next-chunk global_load_lds in flight across the barrier)
#define BAR_PREF  asm volatile("s_waitcnt vmcnt(4) lgkmcnt(0)\n\ts_barrier" ::: "memory")
#define BAR_LAST  asm volatile("s_waitcnt vmcnt(0) lgkmcnt(0)\n\ts_barrier" ::: "memory")
#define BAR_PLAIN asm volatile("s_barrier" ::: "memory")

// fp32 -> bf16 round-to-nearest-even
__device__ __forceinline__ u16 f2bf(float f) {
  union { float f; uint32_t u; } v; v.f = f;
  uint32_t u = v.u;
  u += 0x7fffu + ((u >> 16) & 1u);
  return (u16)(u >> 16);
}
__device__ __forceinline__ float bf2f(u16 u) {
  union { uint32_t u; float f; } v; v.u = ((uint32_t)u) << 16; return v.f;
}

// async global->LDS, 16B per lane; lds dest must be wave-uniform (lane i -> lds + i*16B)
__device__ __forceinline__ void gld_lds16(const u16* g, u16* lds) {
  __builtin_amdgcn_global_load_lds(
      (const __attribute__((address_space(1))) uint32_t*)g,
      (__attribute__((address_space(3))) uint32_t*)lds,
      16, 0, 0);
}

// ---------------- cast: x, Wk, Wq, Wv, Wp -> bf16 ----------------
__global__ __launch_bounds__(256) void cast_all(
    const float* __restrict__ x,  const float* __restrict__ wk,
    const float* __restrict__ wq, const float* __restrict__ wv,
    const float* __restrict__ wp,
    u16* __restrict__ xb, u16* __restrict__ wkb, u16* __restrict__ wqb,
    u16* __restrict__ wvb, u16* __restrict__ wpb) {
  const int NX = NM * NC / 4;   // 1048576 float4s
  const int NW = NC * NC / 4;   // 262144 float4s
  int i = blockIdx.x * 256 + threadIdx.x;
  const float* src; u16* dst; int off;
  if (i < NX)            { src = x;  dst = xb;  off = i; }
  else if (i < NX+NW)    { src = wk; dst = wkb; off = i - NX; }
  else if (i < NX+2*NW)  { src = wq; dst = wqb; off = i - NX - NW; }
  else if (i < NX+3*NW)  { src = wv; dst = wvb; off = i - NX - 2*NW; }
  else if (i < NX+4*NW)  { src = wp; dst = wpb; off = i - NX - 3*NW; }
  else return;
  float4v f = ((const float4v*)src)[off];
  short4v o;
  o.x = (short)f2bf(f.x); o.y = (short)f2bf(f.y);
  o.z = (short)f2bf(f.z); o.w = (short)f2bf(f.w);
  ((short4v*)dst)[off] = o;
}

// ---------------- shared 128x128xK GEMM core: C = A * W^T ----------------
__device__ __forceinline__ void gemm_tile(
    const u16* __restrict__ A_tile, const u16* __restrict__ W_tile,
    u16* As, u16* Bs, float4v (&acc)[4][4]) {
  const int tid  = threadIdx.x;
  const int wave = tid >> 6, lane = tid & 63;
  const int quad = lane >> 4, l15 = lane & 15;
  const int wm = wave >> 1, wn = wave & 1;
  const int c8 = lane & 7, r8 = lane >> 3;

#pragma unroll
  for (int i = 0; i < 4; i++)
#pragma unroll
    for (int j = 0; j < 4; j++) acc[i][j] = (float4v){0.f, 0.f, 0.f, 0.f};

  for (int k0 = 0; k0 < NC; k0 += 64) {
#pragma unroll
    for (int i = 0; i < 4; i++) {
      int row = wave * 32 + i * 8 + r8;
      int gc  = c8 ^ (row & 7);
      gld_lds16(A_tile + row * NC + k0 + gc * 8, As + (wave * 32 + i * 8) * 64);
      gld_lds16(W_tile + row * NC + k0 + gc * 8, Bs + (wave * 32 + i * 8) * 64);
    }
    __syncthreads();
#pragma unroll
    for (int kk = 0; kk < 2; kk++) {
      short8 af[4], bf[4];
#pragma unroll
      for (int mt = 0; mt < 4; mt++) {
        int row = wm * 64 + mt * 16 + l15;
        int ch  = (kk * 4 + quad) ^ (row & 7);
        af[mt] = *(const short8*)(As + row * 64 + ch * 8);
      }
#pragma unroll
      for (int nt = 0; nt < 4; nt++) {
        int row = wn * 64 + nt * 16 + l15;
        int ch  = (kk * 4 + quad) ^ (row & 7);
        bf[nt] = *(const short8*)(Bs + row * 64 + ch * 8);
      }
#pragma unroll
      for (int mt = 0; mt < 4; mt++)
#pragma unroll
        for (int nt = 0; nt < 4; nt++)
          acc[mt][nt] = __builtin_amdgcn_mfma_f32_16x16x32_bf16(af[mt], bf[nt], acc[mt][nt], 0, 0, 0);
    }
    __syncthreads();
  }
}

// ---------------- fused QKV projection ----------------
__global__ __launch_bounds__(256) void qkv_gemm(
    const u16* __restrict__ xb,
    const u16* __restrict__ wqb, const u16* __restrict__ wkb, const u16* __restrict__ wvb,
    const float* __restrict__ bq, const float* __restrict__ bk, const float* __restrict__ bv,
    u16* __restrict__ Q, u16* __restrict__ K, u16* __restrict__ Vb) {
  __shared__ u16 As[128 * 64];
  __shared__ u16 Bs[128 * 64];
  const int nb  = blockIdx.x;
  const int mat = nb >> 3;            // 0=Q 1=K 2=V
  const int n0  = (nb & 7) * 128;
  const int m0  = blockIdx.y * 128;
  const u16*   W    = (mat == 0) ? wqb : (mat == 1) ? wkb : wvb;
  const float* bias = (mat == 0) ? bq  : (mat == 1) ? bk  : bv;
  u16* dst = (mat == 0) ? Q : (mat == 1) ? K : Vb;

  float4v acc[4][4];
  gemm_tile(xb + m0 * NC, W + n0 * NC, As, Bs, acc);

  const int tid = threadIdx.x, wave = tid >> 6, lane = tid & 63;
  const int quad = lane >> 4, l15 = lane & 15;
  const int wm = wave >> 1, wn = wave & 1;
#pragma unroll
  for (int nt = 0; nt < 4; nt++) {
    int col = n0 + wn * 64 + nt * 16 + l15;
    float bval = bias[col];
#pragma unroll
    for (int mt = 0; mt < 4; mt++) {
      int rowb = m0 + wm * 64 + mt * 16 + quad * 4;
#pragma unroll
      for (int r = 0; r < 4; r++)
        dst[(size_t)(rowb + r) * NC + col] = f2bf(acc[mt][nt][r] + bval);
    }
  }
}

// ---------------- V transpose: [4096,1024] -> [B,H,D,T] ----------------
__global__ __launch_bounds__(256) void vtrans(const u16* __restrict__ V, u16* __restrict__ Vt) {
  __shared__ u16 tl[64 * 64];
  const int tid = threadIdx.x;
  const int bh = blockIdx.y, b = bh >> 4, h = bh & 15;
  const int t0 = blockIdx.x * 64;
#pragma unroll
  for (int it = 0; it < 2; it++) {
    int idx = it * 256 + tid;        // 0..511
    int row = idx >> 3;              // t within tile
    int ch  = idx & 7;               // d chunk
    short8 vv = *(const short8*)(V + (size_t)(b * NT + t0 + row) * NC + h * ND + ch * 8);
    int xr = (row >> 3) ^ ch;
    int off = xr * 8 + (row & 7);
#pragma unroll
    for (int j = 0; j < 8; j++) tl[(ch * 8 + j) * 64 + off] = (u16)vv[j];
  }
  __syncthreads();
#pragma unroll
  for (int it = 0; it < 2; it++) {
    int idx = it * 256 + tid;
    int d  = idx >> 3;
    int tc = idx & 7;
    short8 o = *(const short8*)(tl + d * 64 + ((tc ^ ((d >> 3) & 7)) << 3));
    *(short8*)(Vt + (size_t)(bh * ND + d) * NT + t0 + tc * 8) = o;
  }
}

// ---------------- flash attention (causal), S^T formulation ----------------
// Computes S^T = K*Q^T (q = lane&15) so softmax reduces in-lane + 2 shuffle hops,
// m/l/alpha are per-lane scalars, and P^T's C-frag feeds 16x16x16 PV MFMA directly
// (no LDS round-trip). O accumulates transposed: rows d, cols q.
// grid (48, B*H): x<16: tile=x, chunks 0..x, direct write.
//                 x in [16,32): tile=x, seg0 = chunks 0..15 (partial).
//                 x in [32,48): tile=x-16, seg1 = chunks 16..tile (partial, diagonal).
__global__ __launch_bounds__(256) void attn(
    const u16* __restrict__ Q, const u16* __restrict__ K,
    const u16* __restrict__ Vt, u16* __restrict__ O,
    u16* __restrict__ Opart, float* __restrict__ Mpart, float* __restrict__ Lpart) {
  __shared__ u16 Kc[2][64 * 64];   // [s][d] swizzled
  __shared__ u16 Vc[2][64 * 64];   // [d][s] swizzled

  const int tid = threadIdx.x, wave = tid >> 6, lane = tid & 63;
  const int quad = lane >> 4, l15 = lane & 15;
  const int c8 = lane & 7, r8 = lane >> 3;
  const int bh = blockIdx.y, b = bh >> 4, h = bh & 15;
  const int x = blockIdx.x;
  int tile, c_lo, c_hi, seg; bool partial;
  if (x < 16)      { tile = x;      c_lo = 0;  c_hi = x;    partial = false; seg = 0; }
  else if (x < 32) { tile = x;      c_lo = 0;  c_hi = 15;   partial = true;  seg = 0; }
  else             { tile = x - 16; c_lo = 16; c_hi = tile; partial = true;  seg = 1; }
  const int qbase = tile * 64 + wave * 16;
  const float scale = 0.125f;  // 1/sqrt(64)

  // Q fragment (B-operand: n=q=l15, k=d=quad*8+j)
  short8 qf[2];
  {
    const u16* qrow = Q + (size_t)(b * NT + qbase + l15) * NC + h * ND + quad * 8;
    qf[0] = *(const short8*)(qrow);
    qf[1] = *(const short8*)(qrow + 32);
  }

  float m_c = -1e30f, l_c = 0.f;   // per-lane scalars (q = qbase + l15)
  float4v o_acc[4];                // O^T: rows d = dt*16+quad*4+r, col q = l15
#pragma unroll
  for (int dt = 0; dt < 4; dt++) o_acc[dt] = (float4v){0.f, 0.f, 0.f, 0.f};

  auto stage = [&](int ci, int p) {
#pragma unroll
    for (int ii = 0; ii < 2; ii++) {
      int row = wave * 16 + ii * 8 + r8;
      int gc  = c8 ^ (row & 7);
      gld_lds16(K  + (size_t)(b * NT + ci * 64 + row) * NC + h * ND + gc * 8,
                Kc[p] + (wave * 16 + ii * 8) * 64);
      gld_lds16(Vt + (size_t)(bh * ND + row) * NT + ci * 64 + gc * 8,
                Vc[p] + (wave * 16 + ii * 8) * 64);
    }
  };

  stage(c_lo, 0);
  for (int i = c_lo; i <= c_hi; i++) {
    const int p = (i - c_lo) & 1;
    if (i < c_hi) { stage(i + 1, p ^ 1); BAR_PREF; }
    else          { BAR_LAST; }
    const u16* Ks = Kc[p];
    const u16* Vs = Vc[p];

    // S^T = K Q^T : 4 s-subtiles; C rows s_local = quad*4+r, col q = l15
    float sv[4][4];
    const bool mask_iter = (i == tile);
#pragma unroll
    for (int sub = 0; sub < 4; sub++) {
      float4v a = (float4v){0.f, 0.f, 0.f, 0.f};
#pragma unroll
      for (int kk = 0; kk < 2; kk++) {
        int row = sub * 16 + l15;
        int ch  = (kk * 4 + quad) ^ (row & 7);
        short8 kf = *(const short8*)(Ks + row * 64 + ch * 8);
        a = __builtin_amdgcn_mfma_f32_16x16x32_bf16(kf, qf[kk], a, 0, 0, 0);
      }
#pragma unroll
      for (int r = 0; r < 4; r++) {
        float v = a[r] * scale;
        if (mask_iter) {
          int sg = i * 64 + sub * 16 + quad * 4 + r;
          int qg = qbase + l15;
          if (sg > qg) v = -1e30f;
        }
        sv[sub][r] = v;
      }
    }

    // softmax: in-lane max over 16, then 2 cross-quad hops
    float mx = sv[0][0];
#pragma unroll
    for (int sub = 0; sub < 4; sub++)
#pragma unroll
      for (int r = 0; r < 4; r++) mx = fmaxf(mx, sv[sub][r]);
    mx = fmaxf(mx, __shfl_xor(mx, 16));
    mx = fmaxf(mx, __shfl_xor(mx, 32));

    float mnew  = fmaxf(m_c, mx);
    float alpha = __expf(m_c - mnew);

    // P^T fragments: k = quad*4+r matches 16x16x16 B-operand layout directly
    short4v pf[4];
    float rs = 0.f;
#pragma unroll
    for (int sub = 0; sub < 4; sub++)
#pragma unroll
      for (int r = 0; r < 4; r++) {
        float pv = __expf(sv[sub][r] - mnew);
        rs += pv;
        pf[sub][r] = (short)f2bf(pv);
      }
    rs += __shfl_xor(rs, 16);
    rs += __shfl_xor(rs, 32);
    l_c = l_c * alpha + rs;
    m_c = mnew;

#pragma unroll
    for (int dt = 0; dt < 4; dt++)
#pragma unroll
      for (int r = 0; r < 4; r++) o_acc[dt][r] *= alpha;

    // O^T += V^T * P^T  (A = V^T rows d, B = P^T cols q), 16 x 16x16x16
#pragma unroll
    for (int sub = 0; sub < 4; sub++) {
      int chk  = sub * 2 + (quad >> 1);           // s-chunk index (8 elems)
      int boff = (quad & 1) * 8;                  // byte offset within chunk
#pragma unroll
      for (int dt = 0; dt < 4; dt++) {
        int row = dt * 16 + l15;
        int ch  = chk ^ (row & 7);
        short4v vf = *(const short4v*)((const char*)(Vs + row * 64 + ch * 8) + boff);
        o_acc[dt] = MFMA16(vf, pf[sub], o_acc[dt]);
      }
    }
    BAR_PLAIN;  // all waves done reading buf p before next iter's DMA overwrites it
  }

  if (!partial) {
    float inv_l = 1.f / l_c;
    const size_t orow = (size_t)(b * NT + qbase + l15) * NC + h * ND;
#pragma unroll
    for (int dt = 0; dt < 4; dt++) {
      short4v ov;
#pragma unroll
      for (int r = 0; r < 4; r++) ov[r] = (short)f2bf(o_acc[dt][r] * inv_l);
      *(short4v*)(O + orow + dt * 16 + quad * 4) = ov;
    }
  } else {
    int slab = bh * 16 + (tile - 16);
    u16* ob = Opart + ((size_t)seg * 512 + slab) * 4096;
    const int row = wave * 16 + l15;
#pragma unroll
    for (int dt = 0; dt < 4; dt++) {
      short4v ov;
#pragma unroll
      for (int r = 0; r < 4; r++) ov[r] = (short)f2bf(o_acc[dt][r]);
      *(short4v*)(ob + row * 64 + dt * 16 + quad * 4) = ov;   // unnormalized partial
    }
    if (quad == 0) {
      Mpart[(seg * 512 + slab) * 64 + row] = m_c;
      Lpart[(seg * 512 + slab) * 64 + row] = l_c;
    }
  }
}

// ---------------- combine split-s partials ----------------
__global__ __launch_bounds__(256) void combine(
    const u16* __restrict__ Opart, const float* __restrict__ Mp,
    const float* __restrict__ Lp, u16* __restrict__ O) {
  int idx  = blockIdx.x * 256 + threadIdx.x;   // 0..4M-1
  int slab = idx >> 12;
  int rem  = idx & 4095;
  int row  = rem >> 6, d = rem & 63;
  float m0 = Mp[slab * 64 + row], m1 = Mp[(512 + slab) * 64 + row];
  float l0 = Lp[slab * 64 + row], l1 = Lp[(512 + slab) * 64 + row];
  float m  = fmaxf(m0, m1);
  float w0 = __expf(m0 - m), w1 = __expf(m1 - m);
  float o0 = bf2f(Opart[(size_t)slab * 4096 + rem]);
  float o1 = bf2f(Opart[(size_t)(512 + slab) * 4096 + rem]);
  float o  = (w0 * o0 + w1 * o1) / (w0 * l0 + w1 * l1);
  int bh = slab >> 4, tile = 16 + (slab & 15);
  int b = bh >> 4, h = bh & 15;
  int t = tile * 64 + row;
  O[(size_t)(b * NT + t) * NC + h * ND + d] = f2bf(o);
}

// ---------------- output projection ----------------
__global__ __launch_bounds__(256) void out_gemm(
    const u16* __restrict__ Ob, const u16* __restrict__ wpb,
    const float* __restrict__ bp, float* __restrict__ out) {
  __shared__ u16 As[128 * 64];
  __shared__ u16 Bs[128 * 64];
  const int n0 = blockIdx.x * 128;
  const int m0 = blockIdx.y * 128;
  float4v acc[4][4];
  gemm_tile(Ob + m0 * NC, wpb + n0 * NC, As, Bs, acc);

  const int tid = threadIdx.x, wave = tid >> 6, lane = tid & 63;
  const int quad = lane >> 4, l15 = lane & 15;
  const int wm = wave >> 1, wn = wave & 1;
#pragma unroll
  for (int nt = 0; nt < 4; nt++) {
    int col = n0 + wn * 64 + nt * 16 + l15;
    float bval = bp[col];
#pragma unroll
    for (int mt = 0; mt < 4; mt++) {
      int rowb = m0 + wm * 64 + mt * 16 + quad * 4;
#pragma unroll
      for (int r = 0; r < 4; r++)
        out[(rowb + r) * NC + col] = acc[mt][nt][r] + bval;
    }
  }
}

extern "C" void kernel_launch(void* const* d_in, const int* in_sizes, int n_in,
                              void* d_out, int out_size, void* d_ws, size_t ws_size,
                              hipStream_t stream) {
  // setup_inputs order: x, Wk, bk, Wq, bq, Wv, bv, Wp, bp
  const float* x  = (const float*)d_in[0];
  const float* Wk = (const float*)d_in[1];
  const float* bk = (const float*)d_in[2];
  const float* Wq = (const float*)d_in[3];
  const float* bq = (const float*)d_in[4];
  const float* Wv = (const float*)d_in[5];
  const float* bv = (const float*)d_in[6];
  const float* Wp = (const float*)d_in[7];
  const float* bp = (const float*)d_in[8];
  float* out = (float*)d_out;

  uint8_t* ws = (uint8_t*)d_ws;
  const size_t MB = 1u << 20;
  u16* xb    = (u16*)(ws + 0 * MB);
  u16* wkb   = (u16*)(ws + 8 * MB);
  u16* wqb   = (u16*)(ws + 10 * MB);
  u16* wvb   = (u16*)(ws + 12 * MB);
  u16* wpb   = (u16*)(ws + 14 * MB);
  u16* Qb    = (u16*)(ws + 16 * MB);
  u16* Kb    = (u16*)(ws + 24 * MB);
  u16* Vtb   = (u16*)(ws + 32 * MB);   // [B,H,D,T]
  u16* Vb    = (u16*)(ws + 40 * MB);   // row-major V (transient)
  u16* Ob    = (u16*)(ws + 40 * MB);   // attention output, overwrites Vb
  u16* Opart = (u16*)(ws + 0 * MB);    // reuses xb region (8 MB)
  float* Mpart = (float*)(ws + 8 * MB);               // 256 KB
  float* Lpart = (float*)(ws + 8 * MB + 256 * 1024);  // 256 KB

  cast_all<<<8192, 256, 0, stream>>>(x, Wk, Wq, Wv, Wp, xb, wkb, wqb, wvb, wpb);
  qkv_gemm<<<dim3(24, 32), 256, 0, stream>>>(xb, wqb, wkb, wvb, bq, bk, bv, Qb, Kb, Vb);
  vtrans<<<dim3(32, 32), 256, 0, stream>>>(Vb, Vtb);
  attn<<<dim3(48, 32), 256, 0, stream>>>(Qb, Kb, Vtb, Ob, Opart, Mpart, Lpart);
  combine<<<16384, 256, 0, stream>>>(Opart, Mpart, Lpart, Ob);
  out_gemm<<<dim3(8, 32), 256, 0, stream>>>(Ob, wpb, bp, out);
}

// Round 5
// 219.205 us; speedup vs baseline: 1.2120x; 1.0480x over previous
//
#include <hip/hip_runtime.h>
#include <stdint.h>

typedef unsigned short u16;
typedef __attribute__((ext_vector_type(8))) short short8;   // 8 bf16 (4 VGPRs) MFMA A/B frag K=32
typedef __attribute__((ext_vector_type(4))) short short4v;  // 4 bf16 (2 VGPRs) MFMA A/B frag K=16
typedef __attribute__((ext_vector_type(4))) float float4v;  // MFMA C/D frag

#define NB 2
#define NT 2048
#define NC 1024
#define NH 16
#define ND 64
#define NM (NB*NT)   // 4096 rows total

// 16x16x16 bf16 MFMA (2-VGPR operands). Builtin if present, else raw asm.
#if defined(__has_builtin)
#if __has_builtin(__builtin_amdgcn_mfma_f32_16x16x16bf16_1k)
#define MFMA16(a, b, c) __builtin_amdgcn_mfma_f32_16x16x16bf16_1k(a, b, c, 0, 0, 0)
#endif
#endif
#ifndef MFMA16
static __device__ __forceinline__ float4v mfma16_asm(short4v a, short4v b, float4v c) {
  asm volatile("v_mfma_f32_16x16x16_bf16 %0, %1, %2, %0" : "+v"(c) : "v"(a), "v"(b));
  return c;
}
#define MFMA16(a, b, c) mfma16_asm(a, b, c)
#endif

// fine-grained barriers: vmcnt(4) leaves the 4 just-issued next-chunk
// global_load_lds in flight across the barrier
#define BAR_PREF  asm volatile("s_waitcnt vmcnt(4) lgkmcnt(0)\n\ts_barrier" ::: "memory")
#define BAR_LAST  asm volatile("s_waitcnt vmcnt(0) lgkmcnt(0)\n\ts_barrier" ::: "memory")
#define BAR_PLAIN asm volatile("s_barrier" ::: "memory")

// fp32 -> bf16 round-to-nearest-even
__device__ __forceinline__ u16 f2bf(float f) {
  union { float f; uint32_t u; } v; v.f = f;
  uint32_t u = v.u;
  u += 0x7fffu + ((u >> 16) & 1u);
  return (u16)(u >> 16);
}
__device__ __forceinline__ float bf2f(u16 u) {
  union { uint32_t u; float f; } v; v.u = ((uint32_t)u) << 16; return v.f;
}

// pack 4 fp32 -> 4 bf16 (truncation) via 2 v_perm_b32
__device__ __forceinline__ short4v pack4bf(float a, float b, float c, float d) {
  union { uint32_t u[2]; short4v s; } r;
  r.u[0] = __builtin_amdgcn_perm(__float_as_uint(b), __float_as_uint(a), 0x07060302u);
  r.u[1] = __builtin_amdgcn_perm(__float_as_uint(d), __float_as_uint(c), 0x07060302u);
  return r.s;
}

// async global->LDS, 16B per lane; lds dest wave-uniform (lane i -> lds + i*16B)
__device__ __forceinline__ void gld_lds16(const u16* g, u16* lds) {
  __builtin_amdgcn_global_load_lds(
      (const __attribute__((address_space(1))) uint32_t*)g,
      (__attribute__((address_space(3))) uint32_t*)lds,
      16, 0, 0);
}

// ---------------- cast: x, Wk, Wq, Wv, Wp -> bf16 ----------------
__global__ __launch_bounds__(256) void cast_all(
    const float* __restrict__ x,  const float* __restrict__ wk,
    const float* __restrict__ wq, const float* __restrict__ wv,
    const float* __restrict__ wp,
    u16* __restrict__ xb, u16* __restrict__ wkb, u16* __restrict__ wqb,
    u16* __restrict__ wvb, u16* __restrict__ wpb) {
  const int NX = NM * NC / 4;
  const int NW = NC * NC / 4;
  int i = blockIdx.x * 256 + threadIdx.x;
  const float* src; u16* dst; int off;
  if (i < NX)            { src = x;  dst = xb;  off = i; }
  else if (i < NX+NW)    { src = wk; dst = wkb; off = i - NX; }
  else if (i < NX+2*NW)  { src = wq; dst = wqb; off = i - NX - NW; }
  else if (i < NX+3*NW)  { src = wv; dst = wvb; off = i - NX - 2*NW; }
  else if (i < NX+4*NW)  { src = wp; dst = wpb; off = i - NX - 3*NW; }
  else return;
  float4v f = ((const float4v*)src)[off];
  short4v o;
  o.x = (short)f2bf(f.x); o.y = (short)f2bf(f.y);
  o.z = (short)f2bf(f.z); o.w = (short)f2bf(f.w);
  ((short4v*)dst)[off] = o;
}

// ---------------- shared 128x128xK GEMM core: C = A * W^T ----------------
__device__ __forceinline__ void gemm_tile(
    const u16* __restrict__ A_tile, const u16* __restrict__ W_tile,
    u16* As, u16* Bs, float4v (&acc)[4][4]) {
  const int tid  = threadIdx.x;
  const int wave = tid >> 6, lane = tid & 63;
  const int quad = lane >> 4, l15 = lane & 15;
  const int wm = wave >> 1, wn = wave & 1;
  const int c8 = lane & 7, r8 = lane >> 3;

#pragma unroll
  for (int i = 0; i < 4; i++)
#pragma unroll
    for (int j = 0; j < 4; j++) acc[i][j] = (float4v){0.f, 0.f, 0.f, 0.f};

  for (int k0 = 0; k0 < NC; k0 += 64) {
#pragma unroll
    for (int i = 0; i < 4; i++) {
      int row = wave * 32 + i * 8 + r8;
      int gc  = c8 ^ (row & 7);
      gld_lds16(A_tile + row * NC + k0 + gc * 8, As + (wave * 32 + i * 8) * 64);
      gld_lds16(W_tile + row * NC + k0 + gc * 8, Bs + (wave * 32 + i * 8) * 64);
    }
    __syncthreads();
#pragma unroll
    for (int kk = 0; kk < 2; kk++) {
      short8 af[4], bf[4];
#pragma unroll
      for (int mt = 0; mt < 4; mt++) {
        int row = wm * 64 + mt * 16 + l15;
        int ch  = (kk * 4 + quad) ^ (row & 7);
        af[mt] = *(const short8*)(As + row * 64 + ch * 8);
      }
#pragma unroll
      for (int nt = 0; nt < 4; nt++) {
        int row = wn * 64 + nt * 16 + l15;
        int ch  = (kk * 4 + quad) ^ (row & 7);
        bf[nt] = *(const short8*)(Bs + row * 64 + ch * 8);
      }
#pragma unroll
      for (int mt = 0; mt < 4; mt++)
#pragma unroll
        for (int nt = 0; nt < 4; nt++)
          acc[mt][nt] = __builtin_amdgcn_mfma_f32_16x16x32_bf16(af[mt], bf[nt], acc[mt][nt], 0, 0, 0);
    }
    __syncthreads();
  }
}

// ---------------- fused QKV projection ----------------
__global__ __launch_bounds__(256) void qkv_gemm(
    const u16* __restrict__ xb,
    const u16* __restrict__ wqb, const u16* __restrict__ wkb, const u16* __restrict__ wvb,
    const float* __restrict__ bq, const float* __restrict__ bk, const float* __restrict__ bv,
    u16* __restrict__ Q, u16* __restrict__ K, u16* __restrict__ Vb) {
  __shared__ u16 As[128 * 64];
  __shared__ u16 Bs[128 * 64];
  const int nb  = blockIdx.x;
  const int mat = nb >> 3;            // 0=Q 1=K 2=V
  const int n0  = (nb & 7) * 128;
  const int m0  = blockIdx.y * 128;
  const u16*   W    = (mat == 0) ? wqb : (mat == 1) ? wkb : wvb;
  const float* bias = (mat == 0) ? bq  : (mat == 1) ? bk  : bv;
  u16* dst = (mat == 0) ? Q : (mat == 1) ? K : Vb;

  float4v acc[4][4];
  gemm_tile(xb + m0 * NC, W + n0 * NC, As, Bs, acc);

  const int tid = threadIdx.x, wave = tid >> 6, lane = tid & 63;
  const int quad = lane >> 4, l15 = lane & 15;
  const int wm = wave >> 1, wn = wave & 1;
#pragma unroll
  for (int nt = 0; nt < 4; nt++) {
    int col = n0 + wn * 64 + nt * 16 + l15;
    float bval = bias[col];
#pragma unroll
    for (int mt = 0; mt < 4; mt++) {
      int rowb = m0 + wm * 64 + mt * 16 + quad * 4;
#pragma unroll
      for (int r = 0; r < 4; r++)
        dst[(size_t)(rowb + r) * NC + col] = f2bf(acc[mt][nt][r] + bval);
    }
  }
}

// ---------------- V transpose + s-permute: [4096,1024] -> [B,H,D,T'] ----------------
// Within each 64-t chunk, element t-local s is stored at pos = ((s>>2)&3)*16 +
// (s>>4)*4 + (s&3) so attn's PV A-fragments are 2 contiguous b128 per lane.
__global__ __launch_bounds__(256) void vtrans(const u16* __restrict__ V, u16* __restrict__ Vt) {
  __shared__ u16 tl[64 * 64];
  const int tid = threadIdx.x;
  const int bh = blockIdx.y, b = bh >> 4, h = bh & 15;
  const int t0 = blockIdx.x * 64;
#pragma unroll
  for (int it = 0; it < 2; it++) {
    int idx = it * 256 + tid;        // 0..511
    int row = idx >> 3;              // t within tile (= s)
    int ch  = idx & 7;               // d chunk
    short8 vv = *(const short8*)(V + (size_t)(b * NT + t0 + row) * NC + h * ND + ch * 8);
    int p   = ((row >> 2) & 3) * 16 + (row >> 4) * 4 + (row & 3);   // permuted pos
    int off = ((p >> 3) ^ ch) * 8 + (p & 7);                        // swizzle by d>>3 == ch
#pragma unroll
    for (int j = 0; j < 8; j++) tl[(ch * 8 + j) * 64 + off] = (u16)vv[j];
  }
  __syncthreads();
#pragma unroll
  for (int it = 0; it < 2; it++) {
    int idx = it * 256 + tid;
    int d  = idx >> 3;
    int tc = idx & 7;
    short8 o = *(const short8*)(tl + d * 64 + ((tc ^ ((d >> 3) & 7)) << 3));
    *(short8*)(Vt + (size_t)(bh * ND + d) * NT + t0 + tc * 8) = o;
  }
}

// ---------------- flash attention (causal), S^T + 2 q-subtiles/wave ----------------
// 128-row q tiles; wave owns 32 q rows (2 x 16 subtiles sharing all K/V frags).
// grid (24, B*H): x<8: tile=x, chunks 0..2x+1, direct write.
//                 x in [8,16): tile=x, seg0 = chunks 0..15 (partial).
//                 x in [16,24): tile=x-8, seg1 = chunks 16..2t+1 (partial, diag).
__global__ __launch_bounds__(256, 3) void attn(
    const u16* __restrict__ Q, const u16* __restrict__ K,
    const u16* __restrict__ Vt, u16* __restrict__ O,
    u16* __restrict__ Opart, float* __restrict__ Mpart, float* __restrict__ Lpart) {
  __shared__ u16 Kc[2][64 * 64];   // [s][d] swizzled
  __shared__ u16 Vc[2][64 * 64];   // [d][pos(s)] swizzled

  const int tid = threadIdx.x, wave = tid >> 6, lane = tid & 63;
  const int quad = lane >> 4, l15 = lane & 15;
  const int c8 = lane & 7, r8 = lane >> 3;
  const int bh = blockIdx.y, b = bh >> 4, h = bh & 15;
  const int x = blockIdx.x;
  int tile, c_lo, c_hi, seg; bool partial;
  if (x < 8)       { tile = x;     c_lo = 0;  c_hi = 2 * x + 1;    partial = false; seg = 0; }
  else if (x < 16) { tile = x;     c_lo = 0;  c_hi = 15;           partial = true;  seg = 0; }
  else             { tile = x - 8; c_lo = 16; c_hi = 2 * tile + 1; partial = true;  seg = 1; }
  const int qb0 = tile * 128 + wave * 32;
  const float kSc = 0.18033688f;   // 0.125 * log2(e)  (softmax in exp2 domain)

  short8 qf[2][2];
#pragma unroll
  for (int j = 0; j < 2; j++) {
    const u16* qrow = Q + (size_t)(b * NT + qb0 + j * 16 + l15) * NC + h * ND + quad * 8;
    qf[j][0] = *(const short8*)(qrow);
    qf[j][1] = *(const short8*)(qrow + 32);
  }

  float m_c[2] = {-1e30f, -1e30f}, l_c[2] = {0.f, 0.f};  // per-lane (quad-partial l)
  float4v o_acc[2][4];
#pragma unroll
  for (int j = 0; j < 2; j++)
#pragma unroll
    for (int dt = 0; dt < 4; dt++) o_acc[j][dt] = (float4v){0.f, 0.f, 0.f, 0.f};

  // staging: precomputed per-lane offsets, pointer-incremented per chunk
  int kOff[2], vOff[2], ldsOff[2];
#pragma unroll
  for (int ii = 0; ii < 2; ii++) {
    int row = wave * 16 + ii * 8 + r8;
    int gc  = c8 ^ (row & 7);
    kOff[ii]   = row * NC + gc * 8;
    vOff[ii]   = row * NT + gc * 8;
    ldsOff[ii] = (wave * 16 + ii * 8) * 64;
  }
  const u16* kp = K  + (size_t)(b * NT + c_lo * 64) * NC + h * ND;
  const u16* vp = Vt + (size_t)bh * ND * NT + c_lo * 64;

  auto stage = [&](const u16* kpc, const u16* vpc, int p) {
#pragma unroll
    for (int ii = 0; ii < 2; ii++) {
      gld_lds16(kpc + kOff[ii], Kc[p] + ldsOff[ii]);
      gld_lds16(vpc + vOff[ii], Vc[p] + ldsOff[ii]);
    }
  };

  stage(kp, vp, 0);
  for (int i = c_lo; i <= c_hi; i++) {
    const int p = (i - c_lo) & 1;
    if (i < c_hi) { stage(kp + 64 * NC, vp + 64, p ^ 1); BAR_PREF; }
    else          { BAR_LAST; }
    kp += 64 * NC; vp += 64;
    const u16* Ks = Kc[p];
    const u16* Vs = Vc[p];

    // S^T = K Q^T for both subtiles (kf shared)
    float sv[2][4][4];
#pragma unroll
    for (int sub = 0; sub < 4; sub++) {
      float4v a0 = (float4v){0.f, 0.f, 0.f, 0.f};
      float4v a1 = (float4v){0.f, 0.f, 0.f, 0.f};
#pragma unroll
      for (int kk = 0; kk < 2; kk++) {
        int row = sub * 16 + l15;
        int ch  = (kk * 4 + quad) ^ (row & 7);
        short8 kf = *(const short8*)(Ks + row * 64 + ch * 8);
        a0 = __builtin_amdgcn_mfma_f32_16x16x32_bf16(kf, qf[0][kk], a0, 0, 0, 0);
        a1 = __builtin_amdgcn_mfma_f32_16x16x32_bf16(kf, qf[1][kk], a1, 0, 0, 0);
      }
#pragma unroll
      for (int j = 0; j < 2; j++) {
        const float4v& a = (j == 0) ? a0 : a1;
        const bool mj = (i * 64 + 63) > (qb0 + j * 16);   // wave-uniform
        const int qg = qb0 + j * 16 + l15;
#pragma unroll
        for (int r = 0; r < 4; r++) {
          float v = a[r] * kSc;
          if (mj) {
            int sg = i * 64 + sub * 16 + quad * 4 + r;
            if (sg > qg) v = -1e30f;
          }
          sv[j][sub][r] = v;
        }
      }
    }

    // softmax (exp2 domain); l-sum kept quad-partial (reduced in epilogue)
    short4v pf[2][4];
#pragma unroll
    for (int j = 0; j < 2; j++) {
      float mx = sv[j][0][0];
#pragma unroll
      for (int sub = 0; sub < 4; sub++)
#pragma unroll
        for (int r = 0; r < 4; r++) mx = fmaxf(mx, sv[j][sub][r]);
      mx = fmaxf(mx, __shfl_xor(mx, 16));
      mx = fmaxf(mx, __shfl_xor(mx, 32));
      float mnew  = fmaxf(m_c[j], mx);
      float al    = exp2f(m_c[j] - mnew);
      m_c[j] = mnew;
      float rsl = 0.f;
#pragma unroll
      for (int sub = 0; sub < 4; sub++) {
        float p0 = exp2f(sv[j][sub][0] - mnew);
        float p1 = exp2f(sv[j][sub][1] - mnew);
        float p2 = exp2f(sv[j][sub][2] - mnew);
        float p3 = exp2f(sv[j][sub][3] - mnew);
        rsl += (p0 + p1) + (p2 + p3);
        pf[j][sub] = pack4bf(p0, p1, p2, p3);
      }
      l_c[j] = l_c[j] * al + rsl;
#pragma unroll
      for (int dt = 0; dt < 4; dt++)
#pragma unroll
        for (int r = 0; r < 4; r++) o_acc[j][dt][r] *= al;
    }

    // O^T += V^T * P^T : vf = 2 b128/dt (permuted layout), shared by both subtiles
#pragma unroll
    for (int dt = 0; dt < 4; dt++) {
      int row = dt * 16 + l15;
      int swz = row & 7;
      short8 vA = *(const short8*)(Vs + row * 64 + ((2 * quad)     ^ swz) * 8); // subs 0,1
      short8 vB = *(const short8*)(Vs + row * 64 + ((2 * quad + 1) ^ swz) * 8); // subs 2,3
      short4v vA0 = __builtin_shufflevector(vA, vA, 0, 1, 2, 3);
      short4v vA1 = __builtin_shufflevector(vA, vA, 4, 5, 6, 7);
      short4v vB0 = __builtin_shufflevector(vB, vB, 0, 1, 2, 3);
      short4v vB1 = __builtin_shufflevector(vB, vB, 4, 5, 6, 7);
#pragma unroll
      for (int j = 0; j < 2; j++) {
        o_acc[j][dt] = MFMA16(vA0, pf[j][0], o_acc[j][dt]);
        o_acc[j][dt] = MFMA16(vA1, pf[j][1], o_acc[j][dt]);
        o_acc[j][dt] = MFMA16(vB0, pf[j][2], o_acc[j][dt]);
        o_acc[j][dt] = MFMA16(vB1, pf[j][3], o_acc[j][dt]);
      }
    }
    BAR_PLAIN;  // all waves done reading buf p before next DMA overwrites it
  }

  // finalize l: sum the 4 quad-partials per column
  float l_tot[2];
#pragma unroll
  for (int j = 0; j < 2; j++) {
    float t = l_c[j];
    t += __shfl_xor(t, 16);
    t += __shfl_xor(t, 32);
    l_tot[j] = t;
  }

  if (!partial) {
#pragma unroll
    for (int j = 0; j < 2; j++) {
      float inv_l = 1.f / l_tot[j];
      const size_t orow = (size_t)(b * NT + qb0 + j * 16 + l15) * NC + h * ND;
#pragma unroll
      for (int dt = 0; dt < 4; dt++)
        *(short4v*)(O + orow + dt * 16 + quad * 4) =
            pack4bf(o_acc[j][dt][0] * inv_l, o_acc[j][dt][1] * inv_l,
                    o_acc[j][dt][2] * inv_l, o_acc[j][dt][3] * inv_l);
    }
  } else {
    int slab = bh * 8 + (tile - 8);
    u16* ob = Opart + ((size_t)seg * 256 + slab) * 8192;
#pragma unroll
    for (int j = 0; j < 2; j++) {
      const int row = wave * 32 + j * 16 + l15;
#pragma unroll
      for (int dt = 0; dt < 4; dt++)
        *(short4v*)(ob + row * 64 + dt * 16 + quad * 4) =
            pack4bf(o_acc[j][dt][0], o_acc[j][dt][1],
                    o_acc[j][dt][2], o_acc[j][dt][3]);   // unnormalized partial
      if (quad == 0) {
        Mpart[(seg * 256 + slab) * 128 + row] = m_c[j];
        Lpart[(seg * 256 + slab) * 128 + row] = l_tot[j];
      }
    }
  }
}

// ---------------- combine split-s partials (exp2 domain) ----------------
__global__ __launch_bounds__(256) void combine(
    const u16* __restrict__ Opart, const float* __restrict__ Mp,
    const float* __restrict__ Lp, u16* __restrict__ O) {
  int idx  = blockIdx.x * 256 + threadIdx.x;   // 0..2M-1
  int slab = idx >> 13;
  int rem  = idx & 8191;
  int row  = rem >> 6, d = rem & 63;
  float m0 = Mp[slab * 128 + row], m1 = Mp[(256 + slab) * 128 + row];
  float l0 = Lp[slab * 128 + row], l1 = Lp[(256 + slab) * 128 + row];
  float m  = fmaxf(m0, m1);
  float w0 = exp2f(m0 - m), w1 = exp2f(m1 - m);
  float o0 = bf2f(Opart[(size_t)slab * 8192 + rem]);
  float o1 = bf2f(Opart[(size_t)(256 + slab) * 8192 + rem]);
  float o  = (w0 * o0 + w1 * o1) / (w0 * l0 + w1 * l1);
  int bh = slab >> 3, tile = 8 + (slab & 7);
  int b = bh >> 4, h = bh & 15;
  int t = tile * 128 + row;
  O[(size_t)(b * NT + t) * NC + h * ND + d] = f2bf(o);
}

// ---------------- output projection: 64x128 tiles for 2 blocks/CU ----------------
__global__ __launch_bounds__(256) void out_gemm(
    const u16* __restrict__ Ob, const u16* __restrict__ wpb,
    const float* __restrict__ bp, float* __restrict__ out) {
  __shared__ u16 As[64 * 64];
  __shared__ u16 Bs[128 * 64];
  const int n0 = blockIdx.x * 128;
  const int m0 = blockIdx.y * 64;
  const int tid = threadIdx.x, wave = tid >> 6, lane = tid & 63;
  const int quad = lane >> 4, l15 = lane & 15;
  const int wm = wave >> 1, wn = wave & 1;
  const int c8 = lane & 7, r8 = lane >> 3;

  float4v acc[2][4];
#pragma unroll
  for (int i = 0; i < 2; i++)
#pragma unroll
    for (int j = 0; j < 4; j++) acc[i][j] = (float4v){0.f, 0.f, 0.f, 0.f};

  for (int k0 = 0; k0 < NC; k0 += 64) {
#pragma unroll
    for (int i = 0; i < 2; i++) {
      int row = wave * 16 + i * 8 + r8;
      int gc  = c8 ^ (row & 7);
      gld_lds16(Ob + (size_t)(m0 + row) * NC + k0 + gc * 8, As + (wave * 16 + i * 8) * 64);
    }
#pragma unroll
    for (int i = 0; i < 4; i++) {
      int row = wave * 32 + i * 8 + r8;
      int gc  = c8 ^ (row & 7);
      gld_lds16(wpb + (size_t)(n0 + row) * NC + k0 + gc * 8, Bs + (wave * 32 + i * 8) * 64);
    }
    __syncthreads();
#pragma unroll
    for (int kk = 0; kk < 2; kk++) {
      short8 af[2], bf[4];
#pragma unroll
      for (int mt = 0; mt < 2; mt++) {
        int row = wm * 32 + mt * 16 + l15;
        int ch  = (kk * 4 + quad) ^ (row & 7);
        af[mt] = *(const short8*)(As + row * 64 + ch * 8);
      }
#pragma unroll
      for (int nt = 0; nt < 4; nt++) {
        int row = wn * 64 + nt * 16 + l15;
        int ch  = (kk * 4 + quad) ^ (row & 7);
        bf[nt] = *(const short8*)(Bs + row * 64 + ch * 8);
      }
#pragma unroll
      for (int mt = 0; mt < 2; mt++)
#pragma unroll
        for (int nt = 0; nt < 4; nt++)
          acc[mt][nt] = __builtin_amdgcn_mfma_f32_16x16x32_bf16(af[mt], bf[nt], acc[mt][nt], 0, 0, 0);
    }
    __syncthreads();
  }

#pragma unroll
  for (int nt = 0; nt < 4; nt++) {
    int col = n0 + wn * 64 + nt * 16 + l15;
    float bval = bp[col];
#pragma unroll
    for (int mt = 0; mt < 2; mt++) {
      int rowb = m0 + wm * 32 + mt * 16 + quad * 4;
#pragma unroll
      for (int r = 0; r < 4; r++)
        out[(rowb + r) * NC + col] = acc[mt][nt][r] + bval;
    }
  }
}

extern "C" void kernel_launch(void* const* d_in, const int* in_sizes, int n_in,
                              void* d_out, int out_size, void* d_ws, size_t ws_size,
                              hipStream_t stream) {
  // setup_inputs order: x, Wk, bk, Wq, bq, Wv, bv, Wp, bp
  const float* x  = (const float*)d_in[0];
  const float* Wk = (const float*)d_in[1];
  const float* bk = (const float*)d_in[2];
  const float* Wq = (const float*)d_in[3];
  const float* bq = (const float*)d_in[4];
  const float* Wv = (const float*)d_in[5];
  const float* bv = (const float*)d_in[6];
  const float* Wp = (const float*)d_in[7];
  const float* bp = (const float*)d_in[8];
  float* out = (float*)d_out;

  uint8_t* ws = (uint8_t*)d_ws;
  const size_t MB = 1u << 20;
  u16* xb    = (u16*)(ws + 0 * MB);
  u16* wkb   = (u16*)(ws + 8 * MB);
  u16* wqb   = (u16*)(ws + 10 * MB);
  u16* wvb   = (u16*)(ws + 12 * MB);
  u16* wpb   = (u16*)(ws + 14 * MB);
  u16* Qb    = (u16*)(ws + 16 * MB);
  u16* Kb    = (u16*)(ws + 24 * MB);
  u16* Vtb   = (u16*)(ws + 32 * MB);   // [B,H,D,T'] (s-permuted in 64-chunks)
  u16* Vb    = (u16*)(ws + 40 * MB);   // row-major V (transient)
  u16* Ob    = (u16*)(ws + 40 * MB);   // attention output, overwrites Vb
  u16* Opart = (u16*)(ws + 0 * MB);    // reuses xb region (8 MB)
  float* Mpart = (float*)(ws + 8 * MB);               // 256 KB
  float* Lpart = (float*)(ws + 8 * MB + 256 * 1024);  // 256 KB

  cast_all<<<8192, 256, 0, stream>>>(x, Wk, Wq, Wv, Wp, xb, wkb, wqb, wvb, wpb);
  qkv_gemm<<<dim3(24, 32), 256, 0, stream>>>(xb, wqb, wkb, wvb, bq, bk, bv, Qb, Kb, Vb);
  vtrans<<<dim3(32, 32), 256, 0, stream>>>(Vb, Vtb);
  attn<<<dim3(24, 32), 256, 0, stream>>>(Qb, Kb, Vtb, Ob, Opart, Mpart, Lpart);
  combine<<<8192, 256, 0, stream>>>(Opart, Mpart, Lpart, Ob);
  out_gemm<<<dim3(8, 64), 256, 0, stream>>>(Ob, wpb, bp, out);
}